// Round 15
// baseline (184.281 us; speedup 1.0000x reference)
//
#include <hip/hip_runtime.h>
#include <hip/hip_bf16.h>
#include <hip/hip_fp16.h>
#include <math.h>

#define LL 1536
#define NA 14
#define TOPK 30
#define KDIM 3152          // 16 (pos) + 14*14*16 (rbf)
#define KPAD 3200
#define NCHUNK 50          // K chunks of 64

#define TOPK_BLKS 384      // 4 rows per block
#define CONV_BLKS 100
#define NODE_BLKS 384      // 4 rows per block
#define PREP_BLKS (TOPK_BLKS + CONV_BLKS + NODE_BLKS)

#define EDGE_BLKS 768      // 2 residues per block (M = 64 rows); 3 blocks/CU

typedef __attribute__((ext_vector_type(8))) short bf16x8;
typedef __attribute__((ext_vector_type(4))) float f32x4;

// fast exp2 (raw v_exp_f32)
static __device__ __forceinline__ float fexp2(float f) {
    return __builtin_amdgcn_exp2f(f);
}

// packed RNE f32x2 -> bf16x2 (1 instruction; no builtin on gfx950)
static __device__ __forceinline__ unsigned cvt_pk_bf16(float lo, float hi) {
    unsigned r;
    asm("v_cvt_pk_bf16_f32 %0, %1, %2" : "=v"(r) : "v"(lo), "v"(hi));
    return r;
}

static __device__ __forceinline__ unsigned long long u64min(
    unsigned long long a, unsigned long long b) { return a < b ? a : b; }
static __device__ __forceinline__ unsigned long long u64max(
    unsigned long long a, unsigned long long b) { return a < b ? b : a; }

// build 16 RBF values (bf16, mask folded) for one (row, atom-pair), store to LDS
static __device__ __forceinline__ void build_rbf(
    ushort* dst, float4 xi4, float4 xj4,
    const float (&cA)[7], const float (&cB)[7])
{
    float dx = xi4.x - xj4.x, dy = xi4.y - xj4.y, dz = xi4.z - xj4.z;
    float dd = sqrtf(dx * dx + dy * dy + dz * dz + 1e-6f);
    dd = fminf(dd, 27.f);                       // tail < 3e-14: negligible
    float coef = xi4.w * xj4.w;
    float w = fexp2(dd * 2.46219921f);          // exp(1.70667*dd)
    float ev[16];
    float s8 = dd - 10.66666667f;
    ev[0] = fexp2(-0.92332483f * dd * dd) * coef;
    ev[8] = fexp2(-0.92332483f * s8 * s8) * coef;
    #pragma unroll
    for (int j = 1; j <= 7; ++j) {
        ev[j]     = ev[j - 1]     * w * cA[j - 1];
        ev[8 + j] = ev[8 + j - 1] * w * cB[j - 1];
    }
    union { unsigned u[8]; uint4 q[2]; } o;
    #pragma unroll
    for (int c = 0; c < 8; ++c) o.u[c] = cvt_pk_bf16(ev[2 * c], ev[2 * c + 1]);
    *(uint4*)&dst[0] = o.q[0];
    *(uint4*)&dst[8] = o.q[1];
}

// ---------------------------------------------------------------------------
// prep kernel: fuses top-k (+x passthrough), W_edge transpose/convert, node LN
// (unchanged from R13: pair-extraction topk)
// ---------------------------------------------------------------------------
__global__ __launch_bounds__(256) void prep_kernel(
    const float* __restrict__ x, const float* __restrict__ mask,
    const float* __restrict__ feat,
    const float* __restrict__ W_edge, ushort* __restrict__ Wt,
    const float* __restrict__ W_node, const float* __restrict__ gamma_n,
    const float* __restrict__ beta_n, const int* __restrict__ S,
    float* __restrict__ V, float* __restrict__ out_idx, float* __restrict__ out_x)
{
    __shared__ __align__(16) char sm[24576];
    const int blk = blockIdx.x;
    const int tid = threadIdx.x;

    if (blk < TOPK_BLKS) {
        float* ca  = (float*)sm;            // [1536*3]
        float* msk = (float*)sm + 4608;     // [1536]
        for (int t = tid; t < LL; t += 256) {
            msk[t] = mask[t];
            ca[t * 3 + 0] = x[t * 42 + 3];
            ca[t * 3 + 1] = x[t * 42 + 4];
            ca[t * 3 + 2] = x[t * 42 + 5];
        }
        __syncthreads();

        const int lane = tid & 63;
        const int i = blk * 4 + (tid >> 6);
        const float cix = ca[i * 3 + 0], ciy = ca[i * 3 + 1], ciz = ca[i * 3 + 2];
        const float mi = msk[i];

        float d[24], m2a[24];
        float lmax = 0.f;
        #pragma unroll
        for (int c = 0; c < 24; ++c) {
            int j = lane + c * 64;
            float dx = ca[j * 3 + 0] - cix;
            float dy = ca[j * 3 + 1] - ciy;
            float dz = ca[j * 3 + 2] - ciz;
            float m2 = mi * msk[j];
            float D = m2 * sqrtf(dx * dx + dy * dy + dz * dz + 1e-6f);
            d[c] = D; m2a[c] = m2;
            lmax = fmaxf(lmax, D);
        }
        #pragma unroll
        for (int m = 1; m < 64; m <<= 1) lmax = fmaxf(lmax, __shfl_xor(lmax, m));

        unsigned long long key[24];
        #pragma unroll
        for (int c = 0; c < 24; ++c) {
            float adj = d[c] + (1.f - m2a[c]) * lmax;
            key[c] = ((unsigned long long)__float_as_uint(adj) << 32)
                   | (unsigned)(lane + c * 64);
        }

        for (int t = 0; t < TOPK; t += 2) {
            unsigned long long p[12], q[12];
            #pragma unroll
            for (int c = 0; c < 12; ++c) {
                unsigned long long a = key[2 * c], b = key[2 * c + 1];
                p[c] = u64min(a, b); q[c] = u64max(a, b);
            }
            #pragma unroll
            for (int c = 0; c < 6; ++c) {
                unsigned long long hp = u64min(p[2 * c], p[2 * c + 1]);
                unsigned long long hq = u64min(u64max(p[2 * c], p[2 * c + 1]),
                                               u64min(q[2 * c], q[2 * c + 1]));
                p[c] = hp; q[c] = hq;
            }
            #pragma unroll
            for (int c = 0; c < 3; ++c) {
                unsigned long long hp = u64min(p[2 * c], p[2 * c + 1]);
                unsigned long long hq = u64min(u64max(p[2 * c], p[2 * c + 1]),
                                               u64min(q[2 * c], q[2 * c + 1]));
                p[c] = hp; q[c] = hq;
            }
            unsigned long long P = u64min(p[0], p[1]);
            unsigned long long Q = u64min(u64max(p[0], p[1]), u64min(q[0], q[1]));
            unsigned long long P2 = u64min(P, p[2]);
            unsigned long long Q2 = u64min(u64max(P, p[2]), u64min(Q, q[2]));
            #pragma unroll
            for (int m = 1; m < 64; m <<= 1) {
                unsigned long long op = __shfl_xor(P2, m);
                unsigned long long oq = __shfl_xor(Q2, m);
                unsigned long long np = u64min(P2, op);
                unsigned long long nq = u64min(u64max(P2, op), u64min(Q2, oq));
                P2 = np; Q2 = nq;
            }
            if (lane == 0) {
                out_idx[i * TOPK + t]     = (float)(unsigned)(P2 & 0xffffffffu);
                out_idx[i * TOPK + t + 1] = (float)(unsigned)(Q2 & 0xffffffffu);
            }
            #pragma unroll
            for (int c = 0; c < 24; ++c)
                if (key[c] == P2 || key[c] == Q2) key[c] = ~0ull;
        }
        for (int t = lane; t < 42; t += 64) out_x[i * 42 + t] = x[i * 42 + t];

    } else if (blk < TOPK_BLKS + CONV_BLKS) {
        int cb = blk - TOPK_BLKS;
        int k0 = (cb % 50) * 64, n0 = (cb / 50) * 64;
        float (*tile)[65] = (float (*)[65])sm;
        #pragma unroll
        for (int r = 0; r < 16; ++r) {
            int idx = r * 256 + tid;
            int kl = idx >> 6, nl = idx & 63;
            int k = k0 + kl;
            tile[nl][kl] = (k < KDIM) ? W_edge[k * 128 + n0 + nl] : 0.f;
        }
        __syncthreads();
        #pragma unroll
        for (int r = 0; r < 8; ++r) {
            int idx = r * 256 + tid;
            int nl = idx >> 5, kp = (idx & 31) * 2;
            unsigned pk = cvt_pk_bf16(tile[nl][kp], tile[nl][kp + 1]);
            *(unsigned*)&Wt[(size_t)(n0 + nl) * KPAD + k0 + kp] = pk;
        }

    } else {
        int nb = blk - TOPK_BLKS - CONV_BLKS;
        float* f = (float*)sm;                     // [4][128]
        const int w = tid >> 6, lane = tid & 63;
        const int i = nb * 4 + w;
        f[w * 128 + lane] = feat[i * 128 + lane];
        f[w * 128 + 64 + lane] = feat[i * 128 + 64 + lane];
        __syncthreads();
        int s = S[i];
        float a0 = W_node[s * 128 + lane];
        float a1 = W_node[s * 128 + 64 + lane];
        #pragma unroll 8
        for (int c = 0; c < 128; ++c) {
            float fc = f[w * 128 + c];
            a0 = fmaf(fc, W_node[(21 + c) * 128 + lane], a0);
            a1 = fmaf(fc, W_node[(21 + c) * 128 + 64 + lane], a1);
        }
        float ss = a0 + a1, qq = a0 * a0 + a1 * a1;
        #pragma unroll
        for (int m = 1; m < 64; m <<= 1) {
            ss += __shfl_xor(ss, m);
            qq += __shfl_xor(qq, m);
        }
        float mean = ss * (1.f / 128.f);
        float var = qq * (1.f / 128.f) - mean * mean;
        float inv = 1.f / sqrtf(var + 1e-5f);
        V[i * 128 + lane]      = (a0 - mean) * inv * gamma_n[lane] + beta_n[lane];
        V[i * 128 + 64 + lane] = (a1 - mean) * inv * gamma_n[64 + lane] + beta_n[64 + lane];
    }
}

// ---------------------------------------------------------------------------
// edge kernel: block = 2 residues (M=64), C[64x128] = A[64x3200] @ Wt^T.
// B: NO LDS -- inline-asm volatile global_load_dwordx4 straight into VGPRs
//    (can't be sunk by the compiler, unlike R8), consumed after an explicit
//    s_waitcnt vmcnt(0)+sched_barrier. Barriers are raw s_barrier preceded
//    by lgkmcnt(0) ONLY, so in-flight B loads cross them (no vmcnt drain).
// A: built once per value into single LDS As (R9 path). ~25KB LDS.
// ---------------------------------------------------------------------------
__global__ __launch_bounds__(256, 3) void edge_mfma_kernel(
    const float* __restrict__ x, const float* __restrict__ mask,
    const float* __restrict__ a14m, const float* __restrict__ W_pos,
    const float* __restrict__ b_pos, const ushort* __restrict__ Wt,
    const float* __restrict__ gamma, const float* __restrict__ beta,
    const int* __restrict__ R_idx, const int* __restrict__ chain,
    const float* __restrict__ idxf, float* __restrict__ E)
{
    __shared__ __align__(16) ushort As[64 * 72];     //  9216 B
    __shared__ __align__(16) float4 xjr[64][14];     // {x,y,z,mj} 14336 B
    __shared__ __align__(16) float4 xir[2][14];      // {x,y,z,mi}   448 B
    __shared__ int   jl[64];
    __shared__ float lnS[64][2];
    __shared__ float lnQ[64][2];

    const int i0 = blockIdx.x * 2;
    const int tid = threadIdx.x;
    const int wave = tid >> 6, lane = tid & 63;

    // ---- stage jl + xir ----
    if (tid < 64) {
        int g = tid >> 5, e = tid & 31;
        jl[tid] = (e < TOPK) ? (int)idxf[(i0 + g) * TOPK + e] : 0;
    } else if (tid < 64 + 28) {
        int t = tid - 64, g = t / 14, a = t - g * 14;
        const float* xp = &x[(i0 + g) * 42 + a * 3];
        xir[g][a] = make_float4(xp[0], xp[1], xp[2],
                                a14m[(i0 + g) * 14 + a] * mask[i0 + g]);
    }
    __syncthreads();

    // ---- stage xjr (needs jl) ----
    for (int t = tid; t < 64 * 14; t += 256) {
        int row = t / 14, a = t - row * 14;
        int e = row & 31, j = jl[row];
        const float* xp = &x[j * 42 + a * 3];
        float mj = (e < TOPK) ? a14m[j * 14 + a] * mask[j] : 0.f;
        xjr[row][a] = make_float4(xp[0], xp[1], xp[2], mj);
    }
    __syncthreads();

    // ---- roles & constants ----
    const int l16 = lane & 15, lk = lane >> 4, lk8 = lk * 8;
    const int mh = wave >> 1, nh = wave & 1;
    const int arow0 = (mh * 32 + l16) * 72, arow1 = arow0 + 16 * 72;
    const int row_b = tid >> 2, slot = tid & 3;      // build role
    const int gb = row_b >> 5, eb = row_b & 31;
    ushort* bdst = &As[row_b * 72 + slot * 16];

    float cA[7], cB[7];
    #pragma unroll
    for (int j = 1; j <= 7; ++j) {
        cA[j - 1] = __expf(-1.13777778f * (float)(2 * j - 1));
        cB[j - 1] = __expf(-1.13777778f * (float)(2 * (j + 8) - 1));
    }

    // ---- per-lane B pointers: row n = nh*64 + nf*16 + l16, col base lk*8 ----
    const ushort* bp0 = Wt + (size_t)(nh * 64 +  0 + l16) * KPAD + lk8;
    const ushort* bp1 = Wt + (size_t)(nh * 64 + 16 + l16) * KPAD + lk8;
    const ushort* bp2 = Wt + (size_t)(nh * 64 + 32 + l16) * KPAD + lk8;
    const ushort* bp3 = Wt + (size_t)(nh * 64 + 48 + l16) * KPAD + lk8;

    // ---- prologue: build As chunk 0 ----
    if (slot == 0) {                                 // E_pos (cols 0..15)
        float v[16];
        if (eb < TOPK) {
            int i = i0 + gb, j = jl[row_b];
            int off = R_idx[i] - R_idx[j];
            int ec = (chain[i] == chain[j]) ? 1 : 0;
            int dc = off + 32; dc = dc < 0 ? 0 : (dc > 64 ? 64 : dc);
            int d = ec ? dc : 65;
            #pragma unroll
            for (int c = 0; c < 16; ++c) v[c] = W_pos[d * 16 + c] + b_pos[c];
        } else {
            #pragma unroll
            for (int c = 0; c < 16; ++c) v[c] = 0.f;
        }
        union { unsigned u[8]; uint4 q[2]; } o;
        #pragma unroll
        for (int c = 0; c < 8; ++c) o.u[c] = cvt_pk_bf16(v[2 * c], v[2 * c + 1]);
        *(uint4*)&bdst[0] = o.q[0];
        *(uint4*)&bdst[8] = o.q[1];
    } else {
        build_rbf(bdst, xir[gb][0], xjr[row_b][slot - 1], cA, cB);
    }

    int p = slot + 3, a1 = 0, a2 = slot + 3;   // build target: chunk ch+1
    f32x4 acc[2][4] = {};

    __syncthreads();   // As[ch0] visible

    for (int ch = 0; ch < NCHUNK; ++ch) {
        // (i) issue 8 B loads for this chunk (volatile -> cannot be sunk)
        bf16x8 bfr[2][4];
        asm volatile("global_load_dwordx4 %0, %1, off"           : "=v"(bfr[0][0]) : "v"(bp0));
        asm volatile("global_load_dwordx4 %0, %1, off offset:64" : "=v"(bfr[1][0]) : "v"(bp0));
        asm volatile("global_load_dwordx4 %0, %1, off"           : "=v"(bfr[0][1]) : "v"(bp1));
        asm volatile("global_load_dwordx4 %0, %1, off offset:64" : "=v"(bfr[1][1]) : "v"(bp1));
        asm volatile("global_load_dwordx4 %0, %1, off"           : "=v"(bfr[0][2]) : "v"(bp2));
        asm volatile("global_load_dwordx4 %0, %1, off offset:64" : "=v"(bfr[1][2]) : "v"(bp2));
        asm volatile("global_load_dwordx4 %0, %1, off"           : "=v"(bfr[0][3]) : "v"(bp3));
        asm volatile("global_load_dwordx4 %0, %1, off offset:64" : "=v"(bfr[1][3]) : "v"(bp3));

        // (ii) A frag reads from LDS (chunk ch)
        bf16x8 afr[2][2];
        afr[0][0] = *(const bf16x8*)&As[arow0 + lk8];
        afr[0][1] = *(const bf16x8*)&As[arow1 + lk8];
        afr[1][0] = *(const bf16x8*)&As[arow0 + 32 + lk8];
        afr[1][1] = *(const bf16x8*)&As[arow1 + 32 + lk8];

        // barrier WITHOUT vmcnt drain: lgkm only (A reads done), raw s_barrier
        asm volatile("s_waitcnt lgkmcnt(0)" ::: "memory");
        __builtin_amdgcn_sched_barrier(0);
        __builtin_amdgcn_s_barrier();

        // (iii) build As for chunk ch+1 (overlaps B-load latency)
        if (ch + 1 < NCHUNK) {
            if (p <= 195) {
                build_rbf(bdst, xir[gb][a1], xjr[row_b][a2], cA, cB);
            } else {
                uint4 z = {0u, 0u, 0u, 0u};
                *(uint4*)&bdst[0] = z;
                *(uint4*)&bdst[8] = z;
            }
            p += 4; a2 += 4; if (a2 >= 14) { a2 -= 14; ++a1; }
        }

        // (iv) wait for B loads, then MFMA (rule #18: sched_barrier after wait)
        asm volatile("s_waitcnt vmcnt(0)" ::: "memory");
        __builtin_amdgcn_sched_barrier(0);
        #pragma unroll
        for (int ks = 0; ks < 2; ++ks)
            #pragma unroll
            for (int mf = 0; mf < 2; ++mf)
                #pragma unroll
                for (int nf = 0; nf < 4; ++nf)
                    acc[mf][nf] = __builtin_amdgcn_mfma_f32_16x16x32_bf16(
                        afr[ks][mf], bfr[ks][nf], acc[mf][nf], 0, 0, 0);

        // (v) end barrier: builds visible for next iter (lgkm only)
        asm volatile("s_waitcnt lgkmcnt(0)" ::: "memory");
        __builtin_amdgcn_sched_barrier(0);
        __builtin_amdgcn_s_barrier();

        bp0 += 64; bp1 += 64; bp2 += 64; bp3 += 64;   // next chunk (+128 B)
    }

    // ---- LayerNorm epilogue (C/D: col = lane&15, row = (lane>>4)*4+reg) ----
    #pragma unroll
    for (int mf = 0; mf < 2; ++mf)
        #pragma unroll
        for (int reg = 0; reg < 4; ++reg) {
            float s = acc[mf][0][reg] + acc[mf][1][reg] + acc[mf][2][reg] + acc[mf][3][reg];
            float q = acc[mf][0][reg] * acc[mf][0][reg] + acc[mf][1][reg] * acc[mf][1][reg]
                    + acc[mf][2][reg] * acc[mf][2][reg] + acc[mf][3][reg] * acc[mf][3][reg];
            #pragma unroll
            for (int m = 1; m < 16; m <<= 1) {
                s += __shfl_xor(s, m);
                q += __shfl_xor(q, m);
            }
            if (l16 == 0) {
                int row = mh * 32 + mf * 16 + lk * 4 + reg;
                lnS[row][nh] = s;
                lnQ[row][nh] = q;
            }
        }
    __syncthreads();

    float gl[4], bl[4];
    #pragma unroll
    for (int nf = 0; nf < 4; ++nf) {
        int col = nh * 64 + nf * 16 + l16;
        gl[nf] = gamma[col];
        bl[nf] = beta[col];
    }
    #pragma unroll
    for (int mf = 0; mf < 2; ++mf)
        #pragma unroll
        for (int reg = 0; reg < 4; ++reg) {
            int r = mh * 32 + mf * 16 + lk * 4 + reg;
            int e = r & 31, g = r >> 5;
            if (e < TOPK) {
                float s = lnS[r][0] + lnS[r][1];
                float q = lnQ[r][0] + lnQ[r][1];
                float mean = s * (1.f / 128.f);
                float var = q * (1.f / 128.f) - mean * mean;
                float inv = 1.f / sqrtf(var + 1e-5f);
                float* dst = &E[((size_t)((i0 + g) * TOPK + e)) * 128];
                #pragma unroll
                for (int nf = 0; nf < 4; ++nf) {
                    int col = nh * 64 + nf * 16 + l16;
                    dst[col] = (acc[mf][nf][reg] - mean) * inv * gl[nf] + bl[nf];
                }
            }
        }
}

// ---------------------------------------------------------------------------
extern "C" void kernel_launch(void* const* d_in, const int* in_sizes, int n_in,
                              void* d_out, int out_size, void* d_ws, size_t ws_size,
                              hipStream_t stream)
{
    const float* x       = (const float*)d_in[0];
    const float* mask    = (const float*)d_in[1];
    const float* a14m    = (const float*)d_in[2];
    const float* feat    = (const float*)d_in[3];
    const float* W_pos   = (const float*)d_in[4];
    const float* b_pos   = (const float*)d_in[5];
    const float* W_edge  = (const float*)d_in[6];
    const float* gamma_e = (const float*)d_in[7];
    const float* beta_e  = (const float*)d_in[8];
    const float* W_node  = (const float*)d_in[9];
    const float* gamma_n = (const float*)d_in[10];
    const float* beta_n  = (const float*)d_in[11];
    const int*   S       = (const int*)d_in[12];
    const int*   R_idx   = (const int*)d_in[13];
    const int*   chain   = (const int*)d_in[14];

    float* out     = (float*)d_out;
    float* V       = out;                                  // 1536*128
    float* E       = out + 196608;                         // 1536*30*128
    float* out_idx = out + 196608 + 5898240;               // 1536*30
    float* out_x   = out_idx + 46080;                      // 1536*14*3

    ushort* Wt = (ushort*)d_ws;                            // 128*3200 bf16

    prep_kernel<<<PREP_BLKS, 256, 0, stream>>>(
        x, mask, feat, W_edge, Wt, W_node, gamma_n, beta_n, S, V, out_idx, out_x);
    edge_mfma_kernel<<<EDGE_BLKS, 256, 0, stream>>>(
        x, mask, a14m, W_pos, b_pos, Wt, gamma_e, beta_e, R_idx, chain,
        out_idx, E);
}

// Round 16
// 101.586 us; speedup vs baseline: 1.8140x; 1.8140x over previous
//
#include <hip/hip_runtime.h>
#include <hip/hip_bf16.h>
#include <hip/hip_fp16.h>
#include <math.h>

#define LL 1536
#define NA 14
#define TOPK 30
#define KDIM 3152          // 16 (pos) + 14*14*16 (rbf)
#define KPAD 3200
#define NCHUNK 50          // K chunks of 64

#define TOPK_BLKS 384      // 4 rows per block
#define CONV_BLKS 100
#define NODE_BLKS 384      // 4 rows per block
#define PREP_BLKS (TOPK_BLKS + CONV_BLKS + NODE_BLKS)

#define EDGE_BLKS 768      // 2 residues per block (M = 64 rows); 3 blocks/CU

typedef __attribute__((ext_vector_type(8))) short bf16x8;
typedef __attribute__((ext_vector_type(4))) float f32x4;

// fast exp2 (raw v_exp_f32)
static __device__ __forceinline__ float fexp2(float f) {
    return __builtin_amdgcn_exp2f(f);
}

static __device__ __forceinline__ ushort f2bf(float f) {
    union { __hip_bfloat16 h; ushort u; } v;
    v.h = __float2bfloat16(f);
    return v.u;
}

// packed RNE f32x2 -> bf16x2 (1 instruction; no builtin on gfx950)
static __device__ __forceinline__ unsigned cvt_pk_bf16(float lo, float hi) {
    unsigned r;
    asm("v_cvt_pk_bf16_f32 %0, %1, %2" : "=v"(r) : "v"(lo), "v"(hi));
    return r;
}

static __device__ __forceinline__ unsigned long long u64min(
    unsigned long long a, unsigned long long b) { return a < b ? a : b; }

#define ASYNC16(ldsp, gp)                                                     \
    __builtin_amdgcn_global_load_lds(                                         \
        (const __attribute__((address_space(1))) void*)(gp),                  \
        (__attribute__((address_space(3))) void*)(ldsp), 16, 0, 0)

// build 16 RBF values (bf16, mask folded) for one (row, atom-pair), store to LDS
static __device__ __forceinline__ void build_rbf(
    ushort* dst, float4 xi4, float4 xj4,
    const float (&cA)[7], const float (&cB)[7])
{
    float dx = xi4.x - xj4.x, dy = xi4.y - xj4.y, dz = xi4.z - xj4.z;
    float dd = sqrtf(dx * dx + dy * dy + dz * dz + 1e-6f);
    dd = fminf(dd, 27.f);                       // tail < 3e-14: negligible
    float coef = xi4.w * xj4.w;
    float w = fexp2(dd * 2.46219921f);          // exp(1.70667*dd)
    float ev[16];
    float s8 = dd - 10.66666667f;
    ev[0] = fexp2(-0.92332483f * dd * dd) * coef;
    ev[8] = fexp2(-0.92332483f * s8 * s8) * coef;
    #pragma unroll
    for (int j = 1; j <= 7; ++j) {
        ev[j]     = ev[j - 1]     * w * cA[j - 1];
        ev[8 + j] = ev[8 + j - 1] * w * cB[j - 1];
    }
    union { unsigned u[8]; uint4 q[2]; } o;
    #pragma unroll
    for (int c = 0; c < 8; ++c) o.u[c] = cvt_pk_bf16(ev[2 * c], ev[2 * c + 1]);
    *(uint4*)&dst[0] = o.q[0];
    *(uint4*)&dst[8] = o.q[1];
}

// ---------------------------------------------------------------------------
// prep kernel: fuses top-k (+x passthrough), W_edge transpose/convert, node LN
// ---------------------------------------------------------------------------
__global__ __launch_bounds__(256) void prep_kernel(
    const float* __restrict__ x, const float* __restrict__ mask,
    const float* __restrict__ feat,
    const float* __restrict__ W_edge, ushort* __restrict__ Wt,
    const float* __restrict__ W_node, const float* __restrict__ gamma_n,
    const float* __restrict__ beta_n, const int* __restrict__ S,
    float* __restrict__ V, float* __restrict__ out_idx, float* __restrict__ out_x)
{
    __shared__ __align__(16) char sm[24576];
    const int blk = blockIdx.x;
    const int tid = threadIdx.x;

    if (blk < TOPK_BLKS) {
        float* ca  = (float*)sm;            // [1536*3]
        float* msk = (float*)sm + 4608;     // [1536]
        for (int t = tid; t < LL; t += 256) {
            msk[t] = mask[t];
            ca[t * 3 + 0] = x[t * 42 + 3];
            ca[t * 3 + 1] = x[t * 42 + 4];
            ca[t * 3 + 2] = x[t * 42 + 5];
        }
        __syncthreads();

        const int lane = tid & 63;
        const int i = blk * 4 + (tid >> 6);
        const float cix = ca[i * 3 + 0], ciy = ca[i * 3 + 1], ciz = ca[i * 3 + 2];
        const float mi = msk[i];

        float d[24], m2a[24];
        float lmax = 0.f;
        #pragma unroll
        for (int c = 0; c < 24; ++c) {
            int j = lane + c * 64;
            float dx = ca[j * 3 + 0] - cix;
            float dy = ca[j * 3 + 1] - ciy;
            float dz = ca[j * 3 + 2] - ciz;
            float m2 = mi * msk[j];
            float D = m2 * sqrtf(dx * dx + dy * dy + dz * dz + 1e-6f);
            d[c] = D; m2a[c] = m2;
            lmax = fmaxf(lmax, D);
        }
        #pragma unroll
        for (int m = 1; m < 64; m <<= 1) lmax = fmaxf(lmax, __shfl_xor(lmax, m));

        unsigned long long key[24];
        #pragma unroll
        for (int c = 0; c < 24; ++c) {
            float adj = d[c] + (1.f - m2a[c]) * lmax;
            key[c] = ((unsigned long long)__float_as_uint(adj) << 32)
                   | (unsigned)(lane + c * 64);
        }
        for (int t = 0; t < TOPK; ++t) {
            unsigned long long m12[12];
            #pragma unroll
            for (int c = 0; c < 12; ++c) m12[c] = u64min(key[2 * c], key[2 * c + 1]);
            #pragma unroll
            for (int c = 0; c < 6; ++c) m12[c] = u64min(m12[2 * c], m12[2 * c + 1]);
            unsigned long long best = u64min(u64min(m12[0], m12[1]),
                u64min(m12[2], u64min(m12[3], u64min(m12[4], m12[5]))));
            #pragma unroll
            for (int m = 1; m < 64; m <<= 1) best = u64min(best, __shfl_xor(best, m));
            if (lane == 0) out_idx[i * TOPK + t] = (float)(unsigned)(best & 0xffffffffu);
            #pragma unroll
            for (int c = 0; c < 24; ++c) if (key[c] == best) key[c] = ~0ull;
        }
        for (int t = lane; t < 42; t += 64) out_x[i * 42 + t] = x[i * 42 + t];

    } else if (blk < TOPK_BLKS + CONV_BLKS) {
        int cb = blk - TOPK_BLKS;
        int k0 = (cb % 50) * 64, n0 = (cb / 50) * 64;
        float (*tile)[65] = (float (*)[65])sm;
        #pragma unroll
        for (int r = 0; r < 16; ++r) {
            int idx = r * 256 + tid;
            int kl = idx >> 6, nl = idx & 63;
            int k = k0 + kl;
            tile[nl][kl] = (k < KDIM) ? W_edge[k * 128 + n0 + nl] : 0.f;
        }
        __syncthreads();
        #pragma unroll
        for (int r = 0; r < 8; ++r) {
            int idx = r * 256 + tid;
            int nl = idx >> 5, kp = (idx & 31) * 2;
            unsigned pk = cvt_pk_bf16(tile[nl][kp], tile[nl][kp + 1]);
            *(unsigned*)&Wt[(size_t)(n0 + nl) * KPAD + k0 + kp] = pk;
        }

    } else {
        int nb = blk - TOPK_BLKS - CONV_BLKS;
        float* f = (float*)sm;                     // [4][128]
        const int w = tid >> 6, lane = tid & 63;
        const int i = nb * 4 + w;
        f[w * 128 + lane] = feat[i * 128 + lane];
        f[w * 128 + 64 + lane] = feat[i * 128 + 64 + lane];
        __syncthreads();
        int s = S[i];
        float a0 = W_node[s * 128 + lane];
        float a1 = W_node[s * 128 + 64 + lane];
        #pragma unroll 8
        for (int c = 0; c < 128; ++c) {
            float fc = f[w * 128 + c];
            a0 = fmaf(fc, W_node[(21 + c) * 128 + lane], a0);
            a1 = fmaf(fc, W_node[(21 + c) * 128 + 64 + lane], a1);
        }
        float ss = a0 + a1, qq = a0 * a0 + a1 * a1;
        #pragma unroll
        for (int m = 1; m < 64; m <<= 1) {
            ss += __shfl_xor(ss, m);
            qq += __shfl_xor(qq, m);
        }
        float mean = ss * (1.f / 128.f);
        float var = qq * (1.f / 128.f) - mean * mean;
        float inv = 1.f / sqrtf(var + 1e-5f);
        V[i * 128 + lane]      = (a0 - mean) * inv * gamma_n[lane] + beta_n[lane];
        V[i * 128 + 64 + lane] = (a1 - mean) * inv * gamma_n[64 + lane] + beta_n[64 + lane];
    }
}

// ---------------------------------------------------------------------------
// edge kernel (R9, best measured): block = 2 residues (M=64),
// C[64x128] = A[64x3200] @ Wt^T.
// B: single 16KB swizzled Bs via global_load_lds, prefetch ch+1 issued right
//    after barrier-1 (overlaps A-build + MFMA).
// A: built ONCE per value into single LDS As (256 thr = 64 rows x 4 slots,
//    16 vals/thread, 3 exps + cvt_pk), float4 xjr inputs.
// 2 barriers/chunk; single buffers safe: barrier-1's mandatory waitcnt
// drains all frag reads before any overwrite. ~41KB -> 3 blocks/CU.
// ---------------------------------------------------------------------------
__global__ __launch_bounds__(256, 3) void edge_mfma_kernel(
    const float* __restrict__ x, const float* __restrict__ mask,
    const float* __restrict__ a14m, const float* __restrict__ W_pos,
    const float* __restrict__ b_pos, const ushort* __restrict__ Wt,
    const float* __restrict__ gamma, const float* __restrict__ beta,
    const int* __restrict__ R_idx, const int* __restrict__ chain,
    const float* __restrict__ idxf, float* __restrict__ E)
{
    __shared__ __align__(16) ushort Bs[128 * 64];    // 16384 B, swizzled
    __shared__ __align__(16) ushort As[64 * 72];     //  9216 B
    __shared__ __align__(16) float4 xjr[64][14];     // {x,y,z,mj} 14336 B
    __shared__ __align__(16) float4 xir[2][14];      // {x,y,z,mi}   448 B
    __shared__ int   jl[64];
    __shared__ float lnS[64][2];
    __shared__ float lnQ[64][2];

    const int i0 = blockIdx.x * 2;
    const int tid = threadIdx.x;
    const int wave = tid >> 6, lane = tid & 63;

    // ---- stage jl + xir ----
    if (tid < 64) {
        int g = tid >> 5, e = tid & 31;
        jl[tid] = (e < TOPK) ? (int)idxf[(i0 + g) * TOPK + e] : 0;
    } else if (tid < 64 + 28) {
        int t = tid - 64, g = t / 14, a = t - g * 14;
        const float* xp = &x[(i0 + g) * 42 + a * 3];
        xir[g][a] = make_float4(xp[0], xp[1], xp[2],
                                a14m[(i0 + g) * 14 + a] * mask[i0 + g]);
    }
    __syncthreads();

    // ---- stage xjr (needs jl) ----
    for (int t = tid; t < 64 * 14; t += 256) {
        int row = t / 14, a = t - row * 14;
        int e = row & 31, j = jl[row];
        const float* xp = &x[j * 42 + a * 3];
        float mj = (e < TOPK) ? a14m[j * 14 + a] * mask[j] : 0.f;
        xjr[row][a] = make_float4(xp[0], xp[1], xp[2], mj);
    }
    __syncthreads();

    // ---- roles & constants ----
    const int l16 = lane & 15, lk = lane >> 4, lk8 = lk * 8;
    const int mh = wave >> 1, nh = wave & 1;
    const int arow0 = (mh * 32 + l16) * 72, arow1 = arow0 + 16 * 72;
    const int row_b = tid >> 2, slot = tid & 3;      // build role
    const int gb = row_b >> 5, eb = row_b & 31;
    ushort* bdst = &As[row_b * 72 + slot * 16];

    float cA[7], cB[7];
    #pragma unroll
    for (int j = 1; j <= 7; ++j) {
        cA[j - 1] = __expf(-1.13777778f * (float)(2 * j - 1));
        cB[j - 1] = __expf(-1.13777778f * (float)(2 * (j + 8) - 1));
    }

    // ---- Bs staging geometry (pre-swizzled source, linear LDS dest) ----
    const int srow = wave * 32 + (lane >> 3);
    const int sseg = (lane & 7) ^ ((lane >> 3) & 7);
    const ushort* gsrc = Wt + (size_t)srow * KPAD + sseg * 8;

    // ---- prologue: async-stage Bs chunk 0; build As chunk 0 ----
    #pragma unroll
    for (int it = 0; it < 4; ++it)
        ASYNC16(Bs + wave * 2048 + it * 512, gsrc + (size_t)it * 8 * KPAD);

    if (slot == 0) {                                 // E_pos (cols 0..15)
        float v[16];
        if (eb < TOPK) {
            int i = i0 + gb, j = jl[row_b];
            int off = R_idx[i] - R_idx[j];
            int ec = (chain[i] == chain[j]) ? 1 : 0;
            int dc = off + 32; dc = dc < 0 ? 0 : (dc > 64 ? 64 : dc);
            int d = ec ? dc : 65;
            #pragma unroll
            for (int c = 0; c < 16; ++c) v[c] = W_pos[d * 16 + c] + b_pos[c];
        } else {
            #pragma unroll
            for (int c = 0; c < 16; ++c) v[c] = 0.f;
        }
        union { unsigned u[8]; uint4 q[2]; } o;
        #pragma unroll
        for (int c = 0; c < 8; ++c) o.u[c] = cvt_pk_bf16(v[2 * c], v[2 * c + 1]);
        *(uint4*)&bdst[0] = o.q[0];
        *(uint4*)&bdst[8] = o.q[1];
    } else {
        build_rbf(bdst, xir[gb][0], xjr[row_b][slot - 1], cA, cB);
    }

    // B-read offsets (de-swizzle)
    int boff[2][4];
    #pragma unroll
    for (int ks = 0; ks < 2; ++ks)
        #pragma unroll
        for (int nf = 0; nf < 4; ++nf) {
            int n = nh * 64 + nf * 16 + l16;
            boff[ks][nf] = n * 64 + ((((ks << 2) | lk) ^ (n & 7)) << 3);
        }

    int p = slot + 3, a1 = 0, a2 = slot + 3;   // build target: chunk ch+1
    f32x4 acc[2][4] = {};

    __syncthreads();   // drains async (Bs ch0) + ds_writes (As ch0)

    for (int ch = 0; ch < NCHUNK; ++ch) {
        // (i) frag reads -> regs (drained by barrier-1's waitcnt)
        bf16x8 afr[2][2], bfr[2][4];
        #pragma unroll
        for (int ks = 0; ks < 2; ++ks) {
            afr[ks][0] = *(const bf16x8*)&As[arow0 + ks * 32 + lk8];
            afr[ks][1] = *(const bf16x8*)&As[arow1 + ks * 32 + lk8];
            #pragma unroll
            for (int nf = 0; nf < 4; ++nf)
                bfr[ks][nf] = *(const bf16x8*)&Bs[boff[ks][nf]];
        }
        __syncthreads();   // (ii) all reads complete -> buffers free

        // (iii) prefetch Bs ch+1 + build As ch+1 (overlaps MFMA below)
        if (ch + 1 < NCHUNK) {
            #pragma unroll
            for (int it = 0; it < 4; ++it)
                ASYNC16(Bs + wave * 2048 + it * 512,
                        gsrc + (size_t)it * 8 * KPAD + (ch + 1) * 64);
            if (p <= 195) {
                build_rbf(bdst, xir[gb][a1], xjr[row_b][a2], cA, cB);
            } else {
                uint4 z = {0u, 0u, 0u, 0u};
                *(uint4*)&bdst[0] = z;
                *(uint4*)&bdst[8] = z;
            }
            p += 4; a2 += 4; if (a2 >= 14) { a2 -= 14; ++a1; }
        }

        // (iv) MFMA on registers
        #pragma unroll
        for (int ks = 0; ks < 2; ++ks)
            #pragma unroll
            for (int mf = 0; mf < 2; ++mf)
                #pragma unroll
                for (int nf = 0; nf < 4; ++nf)
                    acc[mf][nf] = __builtin_amdgcn_mfma_f32_16x16x32_bf16(
                        afr[ks][mf], bfr[ks][nf], acc[mf][nf], 0, 0, 0);

        __syncthreads();   // (v) drains async + build writes -> next chunk ready
    }

    // ---- LayerNorm epilogue (C/D: col = lane&15, row = (lane>>4)*4+reg) ----
    #pragma unroll
    for (int mf = 0; mf < 2; ++mf)
        #pragma unroll
        for (int reg = 0; reg < 4; ++reg) {
            float s = acc[mf][0][reg] + acc[mf][1][reg] + acc[mf][2][reg] + acc[mf][3][reg];
            float q = acc[mf][0][reg] * acc[mf][0][reg] + acc[mf][1][reg] * acc[mf][1][reg]
                    + acc[mf][2][reg] * acc[mf][2][reg] + acc[mf][3][reg] * acc[mf][3][reg];
            #pragma unroll
            for (int m = 1; m < 16; m <<= 1) {
                s += __shfl_xor(s, m);
                q += __shfl_xor(q, m);
            }
            if (l16 == 0) {
                int row = mh * 32 + mf * 16 + lk * 4 + reg;
                lnS[row][nh] = s;
                lnQ[row][nh] = q;
            }
        }
    __syncthreads();

    float gl[4], bl[4];
    #pragma unroll
    for (int nf = 0; nf < 4; ++nf) {
        int col = nh * 64 + nf * 16 + l16;
        gl[nf] = gamma[col];
        bl[nf] = beta[col];
    }
    #pragma unroll
    for (int mf = 0; mf < 2; ++mf)
        #pragma unroll
        for (int reg = 0; reg < 4; ++reg) {
            int r = mh * 32 + mf * 16 + lk * 4 + reg;
            int e = r & 31, g = r >> 5;
            if (e < TOPK) {
                float s = lnS[r][0] + lnS[r][1];
                float q = lnQ[r][0] + lnQ[r][1];
                float mean = s * (1.f / 128.f);
                float var = q * (1.f / 128.f) - mean * mean;
                float inv = 1.f / sqrtf(var + 1e-5f);
                float* dst = &E[((size_t)((i0 + g) * TOPK + e)) * 128];
                #pragma unroll
                for (int nf = 0; nf < 4; ++nf) {
                    int col = nh * 64 + nf * 16 + l16;
                    dst[col] = (acc[mf][nf][reg] - mean) * inv * gl[nf] + bl[nf];
                }
            }
        }
}

// ---------------------------------------------------------------------------
extern "C" void kernel_launch(void* const* d_in, const int* in_sizes, int n_in,
                              void* d_out, int out_size, void* d_ws, size_t ws_size,
                              hipStream_t stream)
{
    const float* x       = (const float*)d_in[0];
    const float* mask    = (const float*)d_in[1];
    const float* a14m    = (const float*)d_in[2];
    const float* feat    = (const float*)d_in[3];
    const float* W_pos   = (const float*)d_in[4];
    const float* b_pos   = (const float*)d_in[5];
    const float* W_edge  = (const float*)d_in[6];
    const float* gamma_e = (const float*)d_in[7];
    const float* beta_e  = (const float*)d_in[8];
    const float* W_node  = (const float*)d_in[9];
    const float* gamma_n = (const float*)d_in[10];
    const float* beta_n  = (const float*)d_in[11];
    const int*   S       = (const int*)d_in[12];
    const int*   R_idx   = (const int*)d_in[13];
    const int*   chain   = (const int*)d_in[14];

    float* out     = (float*)d_out;
    float* V       = out;                                  // 1536*128
    float* E       = out + 196608;                         // 1536*30*128
    float* out_idx = out + 196608 + 5898240;               // 1536*30
    float* out_x   = out_idx + 46080;                      // 1536*14*3

    ushort* Wt = (ushort*)d_ws;                            // 128*3200 bf16

    prep_kernel<<<PREP_BLKS, 256, 0, stream>>>(
        x, mask, feat, W_edge, Wt, W_node, gamma_n, beta_n, S, V, out_idx, out_x);
    edge_mfma_kernel<<<EDGE_BLKS, 256, 0, stream>>>(
        x, mask, a14m, W_pos, b_pos, Wt, gamma_e, beta_e, R_idx, chain,
        out_idx, E);
}

// Round 17
// 101.001 us; speedup vs baseline: 1.8245x; 1.0058x over previous
//
#include <hip/hip_runtime.h>
#include <hip/hip_bf16.h>
#include <hip/hip_fp16.h>
#include <math.h>

#define LL 1536
#define NA 14
#define TOPK 30
#define KDIM 3152          // 16 (pos) + 14*14*16 (rbf)
#define KPAD 3200
#define NCHUNK 50          // K chunks of 64

#define TOPK_BLKS 384      // 4 rows per block
#define CONV_BLKS 100
#define NODE_BLKS 384      // 4 rows per block
#define PREP_BLKS (TOPK_BLKS + CONV_BLKS + NODE_BLKS)

#define EDGE_BLKS 768      // 2 residues per block (M = 64 rows); 3 blocks/CU

typedef __attribute__((ext_vector_type(8))) short bf16x8;
typedef __attribute__((ext_vector_type(4))) float f32x4;

// fast exp2 (raw v_exp_f32)
static __device__ __forceinline__ float fexp2(float f) {
    return __builtin_amdgcn_exp2f(f);
}

static __device__ __forceinline__ ushort f2bf(float f) {
    union { __hip_bfloat16 h; ushort u; } v;
    v.h = __float2bfloat16(f);
    return v.u;
}

// packed RNE f32x2 -> bf16x2 (1 instruction; no builtin on gfx950)
static __device__ __forceinline__ unsigned cvt_pk_bf16(float lo, float hi) {
    unsigned r;
    asm("v_cvt_pk_bf16_f32 %0, %1, %2" : "=v"(r) : "v"(lo), "v"(hi));
    return r;
}

static __device__ __forceinline__ unsigned long long u64min(
    unsigned long long a, unsigned long long b) { return a < b ? a : b; }

#define ASYNC16(ldsp, gp)                                                     \
    __builtin_amdgcn_global_load_lds(                                         \
        (const __attribute__((address_space(1))) void*)(gp),                  \
        (__attribute__((address_space(3))) void*)(ldsp), 16, 0, 0)

// build 16 RBF values (bf16, mask folded) for one (row, atom-pair), store to LDS
static __device__ __forceinline__ void build_rbf(
    ushort* dst, float4 xi4, float4 xj4,
    const float (&cA)[7], const float (&cB)[7])
{
    float dx = xi4.x - xj4.x, dy = xi4.y - xj4.y, dz = xi4.z - xj4.z;
    float dd = sqrtf(dx * dx + dy * dy + dz * dz + 1e-6f);
    dd = fminf(dd, 27.f);                       // tail < 3e-14: negligible
    float coef = xi4.w * xj4.w;
    float w = fexp2(dd * 2.46219921f);          // exp(1.70667*dd)
    float ev[16];
    float s8 = dd - 10.66666667f;
    ev[0] = fexp2(-0.92332483f * dd * dd) * coef;
    ev[8] = fexp2(-0.92332483f * s8 * s8) * coef;
    #pragma unroll
    for (int j = 1; j <= 7; ++j) {
        ev[j]     = ev[j - 1]     * w * cA[j - 1];
        ev[8 + j] = ev[8 + j - 1] * w * cB[j - 1];
    }
    union { unsigned u[8]; uint4 q[2]; } o;
    #pragma unroll
    for (int c = 0; c < 8; ++c) o.u[c] = cvt_pk_bf16(ev[2 * c], ev[2 * c + 1]);
    *(uint4*)&dst[0] = o.q[0];
    *(uint4*)&dst[8] = o.q[1];
}

// ---------------------------------------------------------------------------
// prep kernel: fuses top-k (+x passthrough), W_edge transpose/convert, node LN
// ---------------------------------------------------------------------------
__global__ __launch_bounds__(256) void prep_kernel(
    const float* __restrict__ x, const float* __restrict__ mask,
    const float* __restrict__ feat,
    const float* __restrict__ W_edge, ushort* __restrict__ Wt,
    const float* __restrict__ W_node, const float* __restrict__ gamma_n,
    const float* __restrict__ beta_n, const int* __restrict__ S,
    float* __restrict__ V, float* __restrict__ out_idx, float* __restrict__ out_x)
{
    __shared__ __align__(16) char sm[24576];
    const int blk = blockIdx.x;
    const int tid = threadIdx.x;

    if (blk < TOPK_BLKS) {
        float* ca  = (float*)sm;            // [1536*3]
        float* msk = (float*)sm + 4608;     // [1536]
        for (int t = tid; t < LL; t += 256) {
            msk[t] = mask[t];
            ca[t * 3 + 0] = x[t * 42 + 3];
            ca[t * 3 + 1] = x[t * 42 + 4];
            ca[t * 3 + 2] = x[t * 42 + 5];
        }
        __syncthreads();

        const int lane = tid & 63;
        const int i = blk * 4 + (tid >> 6);
        const float cix = ca[i * 3 + 0], ciy = ca[i * 3 + 1], ciz = ca[i * 3 + 2];
        const float mi = msk[i];

        float d[24], m2a[24];
        float lmax = 0.f;
        #pragma unroll
        for (int c = 0; c < 24; ++c) {
            int j = lane + c * 64;
            float dx = ca[j * 3 + 0] - cix;
            float dy = ca[j * 3 + 1] - ciy;
            float dz = ca[j * 3 + 2] - ciz;
            float m2 = mi * msk[j];
            float D = m2 * sqrtf(dx * dx + dy * dy + dz * dz + 1e-6f);
            d[c] = D; m2a[c] = m2;
            lmax = fmaxf(lmax, D);
        }
        #pragma unroll
        for (int m = 1; m < 64; m <<= 1) lmax = fmaxf(lmax, __shfl_xor(lmax, m));

        unsigned long long key[24];
        #pragma unroll
        for (int c = 0; c < 24; ++c) {
            float adj = d[c] + (1.f - m2a[c]) * lmax;
            key[c] = ((unsigned long long)__float_as_uint(adj) << 32)
                   | (unsigned)(lane + c * 64);
        }
        for (int t = 0; t < TOPK; ++t) {
            unsigned long long m12[12];
            #pragma unroll
            for (int c = 0; c < 12; ++c) m12[c] = u64min(key[2 * c], key[2 * c + 1]);
            #pragma unroll
            for (int c = 0; c < 6; ++c) m12[c] = u64min(m12[2 * c], m12[2 * c + 1]);
            unsigned long long best = u64min(u64min(m12[0], m12[1]),
                u64min(m12[2], u64min(m12[3], u64min(m12[4], m12[5]))));
            #pragma unroll
            for (int m = 1; m < 64; m <<= 1) best = u64min(best, __shfl_xor(best, m));
            if (lane == 0) out_idx[i * TOPK + t] = (float)(unsigned)(best & 0xffffffffu);
            #pragma unroll
            for (int c = 0; c < 24; ++c) if (key[c] == best) key[c] = ~0ull;
        }
        for (int t = lane; t < 42; t += 64) out_x[i * 42 + t] = x[i * 42 + t];

    } else if (blk < TOPK_BLKS + CONV_BLKS) {
        int cb = blk - TOPK_BLKS;
        int k0 = (cb % 50) * 64, n0 = (cb / 50) * 64;
        float (*tile)[65] = (float (*)[65])sm;
        #pragma unroll
        for (int r = 0; r < 16; ++r) {
            int idx = r * 256 + tid;
            int kl = idx >> 6, nl = idx & 63;
            int k = k0 + kl;
            tile[nl][kl] = (k < KDIM) ? W_edge[k * 128 + n0 + nl] : 0.f;
        }
        __syncthreads();
        #pragma unroll
        for (int r = 0; r < 8; ++r) {
            int idx = r * 256 + tid;
            int nl = idx >> 5, kp = (idx & 31) * 2;
            unsigned pk = cvt_pk_bf16(tile[nl][kp], tile[nl][kp + 1]);
            *(unsigned*)&Wt[(size_t)(n0 + nl) * KPAD + k0 + kp] = pk;
        }

    } else {
        int nb = blk - TOPK_BLKS - CONV_BLKS;
        float* f = (float*)sm;                     // [4][128]
        const int w = tid >> 6, lane = tid & 63;
        const int i = nb * 4 + w;
        f[w * 128 + lane] = feat[i * 128 + lane];
        f[w * 128 + 64 + lane] = feat[i * 128 + 64 + lane];
        __syncthreads();
        int s = S[i];
        float a0 = W_node[s * 128 + lane];
        float a1 = W_node[s * 128 + 64 + lane];
        #pragma unroll 8
        for (int c = 0; c < 128; ++c) {
            float fc = f[w * 128 + c];
            a0 = fmaf(fc, W_node[(21 + c) * 128 + lane], a0);
            a1 = fmaf(fc, W_node[(21 + c) * 128 + 64 + lane], a1);
        }
        float ss = a0 + a1, qq = a0 * a0 + a1 * a1;
        #pragma unroll
        for (int m = 1; m < 64; m <<= 1) {
            ss += __shfl_xor(ss, m);
            qq += __shfl_xor(qq, m);
        }
        float mean = ss * (1.f / 128.f);
        float var = qq * (1.f / 128.f) - mean * mean;
        float inv = 1.f / sqrtf(var + 1e-5f);
        V[i * 128 + lane]      = (a0 - mean) * inv * gamma_n[lane] + beta_n[lane];
        V[i * 128 + 64 + lane] = (a1 - mean) * inv * gamma_n[64 + lane] + beta_n[64 + lane];
    }
}

// ---------------------------------------------------------------------------
// edge kernel (R9 structure + isolated s_setprio around MFMA cluster):
// block = 2 residues (M=64), C[64x128] = A[64x3200] @ Wt^T.
// B: single 16KB swizzled Bs via global_load_lds, prefetch ch+1 issued right
//    after barrier-1 (overlaps A-build + MFMA).
// A: built ONCE per value into single LDS As (256 thr = 64 rows x 4 slots).
// 2 barriers/chunk. ~41KB -> 3 blocks/CU; blocks at independent chunk
// phases give the CU scheduler role-diverse waves -> setprio can pay (T5).
// ---------------------------------------------------------------------------
__global__ __launch_bounds__(256, 3) void edge_mfma_kernel(
    const float* __restrict__ x, const float* __restrict__ mask,
    const float* __restrict__ a14m, const float* __restrict__ W_pos,
    const float* __restrict__ b_pos, const ushort* __restrict__ Wt,
    const float* __restrict__ gamma, const float* __restrict__ beta,
    const int* __restrict__ R_idx, const int* __restrict__ chain,
    const float* __restrict__ idxf, float* __restrict__ E)
{
    __shared__ __align__(16) ushort Bs[128 * 64];    // 16384 B, swizzled
    __shared__ __align__(16) ushort As[64 * 72];     //  9216 B
    __shared__ __align__(16) float4 xjr[64][14];     // {x,y,z,mj} 14336 B
    __shared__ __align__(16) float4 xir[2][14];      // {x,y,z,mi}   448 B
    __shared__ int   jl[64];
    __shared__ float lnS[64][2];
    __shared__ float lnQ[64][2];

    const int i0 = blockIdx.x * 2;
    const int tid = threadIdx.x;
    const int wave = tid >> 6, lane = tid & 63;

    // ---- stage jl + xir ----
    if (tid < 64) {
        int g = tid >> 5, e = tid & 31;
        jl[tid] = (e < TOPK) ? (int)idxf[(i0 + g) * TOPK + e] : 0;
    } else if (tid < 64 + 28) {
        int t = tid - 64, g = t / 14, a = t - g * 14;
        const float* xp = &x[(i0 + g) * 42 + a * 3];
        xir[g][a] = make_float4(xp[0], xp[1], xp[2],
                                a14m[(i0 + g) * 14 + a] * mask[i0 + g]);
    }
    __syncthreads();

    // ---- stage xjr (needs jl) ----
    for (int t = tid; t < 64 * 14; t += 256) {
        int row = t / 14, a = t - row * 14;
        int e = row & 31, j = jl[row];
        const float* xp = &x[j * 42 + a * 3];
        float mj = (e < TOPK) ? a14m[j * 14 + a] * mask[j] : 0.f;
        xjr[row][a] = make_float4(xp[0], xp[1], xp[2], mj);
    }
    __syncthreads();

    // ---- roles & constants ----
    const int l16 = lane & 15, lk = lane >> 4, lk8 = lk * 8;
    const int mh = wave >> 1, nh = wave & 1;
    const int arow0 = (mh * 32 + l16) * 72, arow1 = arow0 + 16 * 72;
    const int row_b = tid >> 2, slot = tid & 3;      // build role
    const int gb = row_b >> 5, eb = row_b & 31;
    ushort* bdst = &As[row_b * 72 + slot * 16];

    float cA[7], cB[7];
    #pragma unroll
    for (int j = 1; j <= 7; ++j) {
        cA[j - 1] = __expf(-1.13777778f * (float)(2 * j - 1));
        cB[j - 1] = __expf(-1.13777778f * (float)(2 * (j + 8) - 1));
    }

    // ---- Bs staging geometry (pre-swizzled source, linear LDS dest) ----
    const int srow = wave * 32 + (lane >> 3);
    const int sseg = (lane & 7) ^ ((lane >> 3) & 7);
    const ushort* gsrc = Wt + (size_t)srow * KPAD + sseg * 8;

    // ---- prologue: async-stage Bs chunk 0; build As chunk 0 ----
    #pragma unroll
    for (int it = 0; it < 4; ++it)
        ASYNC16(Bs + wave * 2048 + it * 512, gsrc + (size_t)it * 8 * KPAD);

    if (slot == 0) {                                 // E_pos (cols 0..15)
        float v[16];
        if (eb < TOPK) {
            int i = i0 + gb, j = jl[row_b];
            int off = R_idx[i] - R_idx[j];
            int ec = (chain[i] == chain[j]) ? 1 : 0;
            int dc = off + 32; dc = dc < 0 ? 0 : (dc > 64 ? 64 : dc);
            int d = ec ? dc : 65;
            #pragma unroll
            for (int c = 0; c < 16; ++c) v[c] = W_pos[d * 16 + c] + b_pos[c];
        } else {
            #pragma unroll
            for (int c = 0; c < 16; ++c) v[c] = 0.f;
        }
        union { unsigned u[8]; uint4 q[2]; } o;
        #pragma unroll
        for (int c = 0; c < 8; ++c) o.u[c] = cvt_pk_bf16(v[2 * c], v[2 * c + 1]);
        *(uint4*)&bdst[0] = o.q[0];
        *(uint4*)&bdst[8] = o.q[1];
    } else {
        build_rbf(bdst, xir[gb][0], xjr[row_b][slot - 1], cA, cB);
    }

    // B-read offsets (de-swizzle)
    int boff[2][4];
    #pragma unroll
    for (int ks = 0; ks < 2; ++ks)
        #pragma unroll
        for (int nf = 0; nf < 4; ++nf) {
            int n = nh * 64 + nf * 16 + l16;
            boff[ks][nf] = n * 64 + ((((ks << 2) | lk) ^ (n & 7)) << 3);
        }

    int p = slot + 3, a1 = 0, a2 = slot + 3;   // build target: chunk ch+1
    f32x4 acc[2][4] = {};

    __syncthreads();   // drains async (Bs ch0) + ds_writes (As ch0)

    for (int ch = 0; ch < NCHUNK; ++ch) {
        // (i) frag reads -> regs (drained by barrier-1's waitcnt)
        bf16x8 afr[2][2], bfr[2][4];
        #pragma unroll
        for (int ks = 0; ks < 2; ++ks) {
            afr[ks][0] = *(const bf16x8*)&As[arow0 + ks * 32 + lk8];
            afr[ks][1] = *(const bf16x8*)&As[arow1 + ks * 32 + lk8];
            #pragma unroll
            for (int nf = 0; nf < 4; ++nf)
                bfr[ks][nf] = *(const bf16x8*)&Bs[boff[ks][nf]];
        }
        __syncthreads();   // (ii) all reads complete -> buffers free

        // (iii) prefetch Bs ch+1 + build As ch+1 (overlaps MFMA below)
        if (ch + 1 < NCHUNK) {
            #pragma unroll
            for (int it = 0; it < 4; ++it)
                ASYNC16(Bs + wave * 2048 + it * 512,
                        gsrc + (size_t)it * 8 * KPAD + (ch + 1) * 64);
            if (p <= 195) {
                build_rbf(bdst, xir[gb][a1], xjr[row_b][a2], cA, cB);
            } else {
                uint4 z = {0u, 0u, 0u, 0u};
                *(uint4*)&bdst[0] = z;
                *(uint4*)&bdst[8] = z;
            }
            p += 4; a2 += 4; if (a2 >= 14) { a2 -= 14; ++a1; }
        }

        // (iv) MFMA on registers (priority-boosted; blocks are phase-diverse)
        __builtin_amdgcn_s_setprio(1);
        #pragma unroll
        for (int ks = 0; ks < 2; ++ks)
            #pragma unroll
            for (int mf = 0; mf < 2; ++mf)
                #pragma unroll
                for (int nf = 0; nf < 4; ++nf)
                    acc[mf][nf] = __builtin_amdgcn_mfma_f32_16x16x32_bf16(
                        afr[ks][mf], bfr[ks][nf], acc[mf][nf], 0, 0, 0);
        __builtin_amdgcn_s_setprio(0);

        __syncthreads();   // (v) drains async + build writes -> next chunk ready
    }

    // ---- LayerNorm epilogue (C/D: col = lane&15, row = (lane>>4)*4+reg) ----
    #pragma unroll
    for (int mf = 0; mf < 2; ++mf)
        #pragma unroll
        for (int reg = 0; reg < 4; ++reg) {
            float s = acc[mf][0][reg] + acc[mf][1][reg] + acc[mf][2][reg] + acc[mf][3][reg];
            float q = acc[mf][0][reg] * acc[mf][0][reg] + acc[mf][1][reg] * acc[mf][1][reg]
                    + acc[mf][2][reg] * acc[mf][2][reg] + acc[mf][3][reg] * acc[mf][3][reg];
            #pragma unroll
            for (int m = 1; m < 16; m <<= 1) {
                s += __shfl_xor(s, m);
                q += __shfl_xor(q, m);
            }
            if (l16 == 0) {
                int row = mh * 32 + mf * 16 + lk * 4 + reg;
                lnS[row][nh] = s;
                lnQ[row][nh] = q;
            }
        }
    __syncthreads();

    float gl[4], bl[4];
    #pragma unroll
    for (int nf = 0; nf < 4; ++nf) {
        int col = nh * 64 + nf * 16 + l16;
        gl[nf] = gamma[col];
        bl[nf] = beta[col];
    }
    #pragma unroll
    for (int mf = 0; mf < 2; ++mf)
        #pragma unroll
        for (int reg = 0; reg < 4; ++reg) {
            int r = mh * 32 + mf * 16 + lk * 4 + reg;
            int e = r & 31, g = r >> 5;
            if (e < TOPK) {
                float s = lnS[r][0] + lnS[r][1];
                float q = lnQ[r][0] + lnQ[r][1];
                float mean = s * (1.f / 128.f);
                float var = q * (1.f / 128.f) - mean * mean;
                float inv = 1.f / sqrtf(var + 1e-5f);
                float* dst = &E[((size_t)((i0 + g) * TOPK + e)) * 128];
                #pragma unroll
                for (int nf = 0; nf < 4; ++nf) {
                    int col = nh * 64 + nf * 16 + l16;
                    dst[col] = (acc[mf][nf][reg] - mean) * inv * gl[nf] + bl[nf];
                }
            }
        }
}

// ---------------------------------------------------------------------------
extern "C" void kernel_launch(void* const* d_in, const int* in_sizes, int n_in,
                              void* d_out, int out_size, void* d_ws, size_t ws_size,
                              hipStream_t stream)
{
    const float* x       = (const float*)d_in[0];
    const float* mask    = (const float*)d_in[1];
    const float* a14m    = (const float*)d_in[2];
    const float* feat    = (const float*)d_in[3];
    const float* W_pos   = (const float*)d_in[4];
    const float* b_pos   = (const float*)d_in[5];
    const float* W_edge  = (const float*)d_in[6];
    const float* gamma_e = (const float*)d_in[7];
    const float* beta_e  = (const float*)d_in[8];
    const float* W_node  = (const float*)d_in[9];
    const float* gamma_n = (const float*)d_in[10];
    const float* beta_n  = (const float*)d_in[11];
    const int*   S       = (const int*)d_in[12];
    const int*   R_idx   = (const int*)d_in[13];
    const int*   chain   = (const int*)d_in[14];

    float* out     = (float*)d_out;
    float* V       = out;                                  // 1536*128
    float* E       = out + 196608;                         // 1536*30*128
    float* out_idx = out + 196608 + 5898240;               // 1536*30
    float* out_x   = out_idx + 46080;                      // 1536*14*3

    ushort* Wt = (ushort*)d_ws;                            // 128*3200 bf16

    prep_kernel<<<PREP_BLKS, 256, 0, stream>>>(
        x, mask, feat, W_edge, Wt, W_node, gamma_n, beta_n, S, V, out_idx, out_x);
    edge_mfma_kernel<<<EDGE_BLKS, 256, 0, stream>>>(
        x, mask, a14m, W_pos, b_pos, Wt, gamma_e, beta_e, R_idx, chain,
        out_idx, E);
}

// Round 18
// 100.143 us; speedup vs baseline: 1.8402x; 1.0086x over previous
//
#include <hip/hip_runtime.h>
#include <hip/hip_bf16.h>
#include <hip/hip_fp16.h>
#include <math.h>

#define LL 1536
#define NA 14
#define TOPK 30
#define KDIM 3152          // 16 (pos) + 14*14*16 (rbf)
#define KPAD 3200
#define NCHUNK 50          // K chunks of 64

#define TOPK_BLKS 192      // 8 rows per block, 1 row per wave (512 thr)
#define CONV_BLKS 100
#define NODE_BLKS 192      // 8 rows per block
#define PREP_BLKS (TOPK_BLKS + CONV_BLKS + NODE_BLKS)

#define EDGE_BLKS 768      // 2 residues per block (M = 64 rows); 3 blocks/CU

typedef __attribute__((ext_vector_type(8))) short bf16x8;
typedef __attribute__((ext_vector_type(4))) float f32x4;

// fast exp2 (raw v_exp_f32)
static __device__ __forceinline__ float fexp2(float f) {
    return __builtin_amdgcn_exp2f(f);
}

// packed RNE f32x2 -> bf16x2 (1 instruction; no builtin on gfx950)
static __device__ __forceinline__ unsigned cvt_pk_bf16(float lo, float hi) {
    unsigned r;
    asm("v_cvt_pk_bf16_f32 %0, %1, %2" : "=v"(r) : "v"(lo), "v"(hi));
    return r;
}

static __device__ __forceinline__ unsigned long long u64min(
    unsigned long long a, unsigned long long b) { return a < b ? a : b; }

#define ASYNC16(ldsp, gp)                                                     \
    __builtin_amdgcn_global_load_lds(                                         \
        (const __attribute__((address_space(1))) void*)(gp),                  \
        (__attribute__((address_space(3))) void*)(ldsp), 16, 0, 0)

// build 16 RBF values (bf16, mask folded) for one (row, atom-pair), store to LDS
static __device__ __forceinline__ void build_rbf(
    ushort* dst, float4 xi4, float4 xj4,
    const float (&cA)[7], const float (&cB)[7])
{
    float dx = xi4.x - xj4.x, dy = xi4.y - xj4.y, dz = xi4.z - xj4.z;
    float dd = sqrtf(dx * dx + dy * dy + dz * dz + 1e-6f);
    dd = fminf(dd, 27.f);                       // tail < 3e-14: negligible
    float coef = xi4.w * xj4.w;
    float w = fexp2(dd * 2.46219921f);          // exp(1.70667*dd)
    float ev[16];
    float s8 = dd - 10.66666667f;
    ev[0] = fexp2(-0.92332483f * dd * dd) * coef;
    ev[8] = fexp2(-0.92332483f * s8 * s8) * coef;
    #pragma unroll
    for (int j = 1; j <= 7; ++j) {
        ev[j]     = ev[j - 1]     * w * cA[j - 1];
        ev[8 + j] = ev[8 + j - 1] * w * cB[j - 1];
    }
    union { unsigned u[8]; uint4 q[2]; } o;
    #pragma unroll
    for (int c = 0; c < 8; ++c) o.u[c] = cvt_pk_bf16(ev[2 * c], ev[2 * c + 1]);
    *(uint4*)&dst[0] = o.q[0];
    *(uint4*)&dst[8] = o.q[1];
}

// ---------------------------------------------------------------------------
// prep kernel (512 threads): top-k (8 rows/block, 1 row/wave -- per-wave
// algorithm identical to the proven 256-thread version, just 2x fewer blocks
// re-staging the 24.6KB ca/msk tile), W_edge transpose/convert, node LN.
// ---------------------------------------------------------------------------
__global__ __launch_bounds__(512) void prep_kernel(
    const float* __restrict__ x, const float* __restrict__ mask,
    const float* __restrict__ feat,
    const float* __restrict__ W_edge, ushort* __restrict__ Wt,
    const float* __restrict__ W_node, const float* __restrict__ gamma_n,
    const float* __restrict__ beta_n, const int* __restrict__ S,
    float* __restrict__ V, float* __restrict__ out_idx, float* __restrict__ out_x)
{
    __shared__ __align__(16) char sm[24576];
    const int blk = blockIdx.x;
    const int tid = threadIdx.x;
    const int wave = tid >> 6, lane = tid & 63;

    if (blk < TOPK_BLKS) {
        float* ca  = (float*)sm;            // [1536*3]
        float* msk = (float*)sm + 4608;     // [1536]
        for (int t = tid; t < LL; t += 512) {
            msk[t] = mask[t];
            ca[t * 3 + 0] = x[t * 42 + 3];
            ca[t * 3 + 1] = x[t * 42 + 4];
            ca[t * 3 + 2] = x[t * 42 + 5];
        }
        __syncthreads();

        const int i = blk * 8 + wave;
        const float cix = ca[i * 3 + 0], ciy = ca[i * 3 + 1], ciz = ca[i * 3 + 2];
        const float mi = msk[i];

        float d[24], m2a[24];
        float lmax = 0.f;
        #pragma unroll
        for (int c = 0; c < 24; ++c) {
            int j = lane + c * 64;
            float dx = ca[j * 3 + 0] - cix;
            float dy = ca[j * 3 + 1] - ciy;
            float dz = ca[j * 3 + 2] - ciz;
            float m2 = mi * msk[j];
            float D = m2 * sqrtf(dx * dx + dy * dy + dz * dz + 1e-6f);
            d[c] = D; m2a[c] = m2;
            lmax = fmaxf(lmax, D);
        }
        #pragma unroll
        for (int m = 1; m < 64; m <<= 1) lmax = fmaxf(lmax, __shfl_xor(lmax, m));

        unsigned long long key[24];
        #pragma unroll
        for (int c = 0; c < 24; ++c) {
            float adj = d[c] + (1.f - m2a[c]) * lmax;
            key[c] = ((unsigned long long)__float_as_uint(adj) << 32)
                   | (unsigned)(lane + c * 64);
        }
        for (int t = 0; t < TOPK; ++t) {
            unsigned long long m12[12];
            #pragma unroll
            for (int c = 0; c < 12; ++c) m12[c] = u64min(key[2 * c], key[2 * c + 1]);
            #pragma unroll
            for (int c = 0; c < 6; ++c) m12[c] = u64min(m12[2 * c], m12[2 * c + 1]);
            unsigned long long best = u64min(u64min(m12[0], m12[1]),
                u64min(m12[2], u64min(m12[3], u64min(m12[4], m12[5]))));
            #pragma unroll
            for (int m = 1; m < 64; m <<= 1) best = u64min(best, __shfl_xor(best, m));
            if (lane == 0) out_idx[i * TOPK + t] = (float)(unsigned)(best & 0xffffffffu);
            #pragma unroll
            for (int c = 0; c < 24; ++c) if (key[c] == best) key[c] = ~0ull;
        }
        for (int t = lane; t < 42; t += 64) out_x[i * 42 + t] = x[i * 42 + t];

    } else if (blk < TOPK_BLKS + CONV_BLKS) {
        int cb = blk - TOPK_BLKS;
        int k0 = (cb % 50) * 64, n0 = (cb / 50) * 64;
        float (*tile)[65] = (float (*)[65])sm;
        #pragma unroll
        for (int r = 0; r < 8; ++r) {
            int idx = r * 512 + tid;
            int kl = idx >> 6, nl = idx & 63;
            int k = k0 + kl;
            tile[nl][kl] = (k < KDIM) ? W_edge[k * 128 + n0 + nl] : 0.f;
        }
        __syncthreads();
        #pragma unroll
        for (int r = 0; r < 4; ++r) {
            int idx = r * 512 + tid;
            int nl = idx >> 5, kp = (idx & 31) * 2;
            unsigned pk = cvt_pk_bf16(tile[nl][kp], tile[nl][kp + 1]);
            *(unsigned*)&Wt[(size_t)(n0 + nl) * KPAD + k0 + kp] = pk;
        }

    } else {
        int nb = blk - TOPK_BLKS - CONV_BLKS;
        float* f = (float*)sm;                     // [8][128]
        const int i = nb * 8 + wave;
        f[wave * 128 + lane] = feat[i * 128 + lane];
        f[wave * 128 + 64 + lane] = feat[i * 128 + 64 + lane];
        __syncthreads();
        int s = S[i];
        float a0 = W_node[s * 128 + lane];
        float a1 = W_node[s * 128 + 64 + lane];
        #pragma unroll 8
        for (int c = 0; c < 128; ++c) {
            float fc = f[wave * 128 + c];
            a0 = fmaf(fc, W_node[(21 + c) * 128 + lane], a0);
            a1 = fmaf(fc, W_node[(21 + c) * 128 + 64 + lane], a1);
        }
        float ss = a0 + a1, qq = a0 * a0 + a1 * a1;
        #pragma unroll
        for (int m = 1; m < 64; m <<= 1) {
            ss += __shfl_xor(ss, m);
            qq += __shfl_xor(qq, m);
        }
        float mean = ss * (1.f / 128.f);
        float var = qq * (1.f / 128.f) - mean * mean;
        float inv = 1.f / sqrtf(var + 1e-5f);
        V[i * 128 + lane]      = (a0 - mean) * inv * gamma_n[lane] + beta_n[lane];
        V[i * 128 + 64 + lane] = (a1 - mean) * inv * gamma_n[64 + lane] + beta_n[64 + lane];
    }
}

// ---------------------------------------------------------------------------
// edge kernel (R9 structure + setprio; best measured): block = 2 residues
// (M=64), C[64x128] = A[64x3200] @ Wt^T.
// B: single 16KB swizzled Bs via global_load_lds, prefetch ch+1 after
//    barrier-1. A: built once per value into single LDS As. 2 barriers/chunk.
// ~41KB -> 3 blocks/CU; blocks at independent chunk phases -> setprio pays.
// ---------------------------------------------------------------------------
__global__ __launch_bounds__(256, 3) void edge_mfma_kernel(
    const float* __restrict__ x, const float* __restrict__ mask,
    const float* __restrict__ a14m, const float* __restrict__ W_pos,
    const float* __restrict__ b_pos, const ushort* __restrict__ Wt,
    const float* __restrict__ gamma, const float* __restrict__ beta,
    const int* __restrict__ R_idx, const int* __restrict__ chain,
    const float* __restrict__ idxf, float* __restrict__ E)
{
    __shared__ __align__(16) ushort Bs[128 * 64];    // 16384 B, swizzled
    __shared__ __align__(16) ushort As[64 * 72];     //  9216 B
    __shared__ __align__(16) float4 xjr[64][14];     // {x,y,z,mj} 14336 B
    __shared__ __align__(16) float4 xir[2][14];      // {x,y,z,mi}   448 B
    __shared__ int   jl[64];
    __shared__ float lnS[64][2];
    __shared__ float lnQ[64][2];

    const int i0 = blockIdx.x * 2;
    const int tid = threadIdx.x;
    const int wave = tid >> 6, lane = tid & 63;

    // ---- stage jl + xir ----
    if (tid < 64) {
        int g = tid >> 5, e = tid & 31;
        jl[tid] = (e < TOPK) ? (int)idxf[(i0 + g) * TOPK + e] : 0;
    } else if (tid < 64 + 28) {
        int t = tid - 64, g = t / 14, a = t - g * 14;
        const float* xp = &x[(i0 + g) * 42 + a * 3];
        xir[g][a] = make_float4(xp[0], xp[1], xp[2],
                                a14m[(i0 + g) * 14 + a] * mask[i0 + g]);
    }
    __syncthreads();

    // ---- stage xjr (needs jl) ----
    for (int t = tid; t < 64 * 14; t += 256) {
        int row = t / 14, a = t - row * 14;
        int e = row & 31, j = jl[row];
        const float* xp = &x[j * 42 + a * 3];
        float mj = (e < TOPK) ? a14m[j * 14 + a] * mask[j] : 0.f;
        xjr[row][a] = make_float4(xp[0], xp[1], xp[2], mj);
    }
    __syncthreads();

    // ---- roles & constants ----
    const int l16 = lane & 15, lk = lane >> 4, lk8 = lk * 8;
    const int mh = wave >> 1, nh = wave & 1;
    const int arow0 = (mh * 32 + l16) * 72, arow1 = arow0 + 16 * 72;
    const int row_b = tid >> 2, slot = tid & 3;      // build role
    const int gb = row_b >> 5, eb = row_b & 31;
    ushort* bdst = &As[row_b * 72 + slot * 16];

    float cA[7], cB[7];
    #pragma unroll
    for (int j = 1; j <= 7; ++j) {
        cA[j - 1] = __expf(-1.13777778f * (float)(2 * j - 1));
        cB[j - 1] = __expf(-1.13777778f * (float)(2 * (j + 8) - 1));
    }

    // ---- Bs staging geometry (pre-swizzled source, linear LDS dest) ----
    const int srow = wave * 32 + (lane >> 3);
    const int sseg = (lane & 7) ^ ((lane >> 3) & 7);
    const ushort* gsrc = Wt + (size_t)srow * KPAD + sseg * 8;

    // ---- prologue: async-stage Bs chunk 0; build As chunk 0 ----
    #pragma unroll
    for (int it = 0; it < 4; ++it)
        ASYNC16(Bs + wave * 2048 + it * 512, gsrc + (size_t)it * 8 * KPAD);

    if (slot == 0) {                                 // E_pos (cols 0..15)
        float v[16];
        if (eb < TOPK) {
            int i = i0 + gb, j = jl[row_b];
            int off = R_idx[i] - R_idx[j];
            int ec = (chain[i] == chain[j]) ? 1 : 0;
            int dc = off + 32; dc = dc < 0 ? 0 : (dc > 64 ? 64 : dc);
            int d = ec ? dc : 65;
            #pragma unroll
            for (int c = 0; c < 16; ++c) v[c] = W_pos[d * 16 + c] + b_pos[c];
        } else {
            #pragma unroll
            for (int c = 0; c < 16; ++c) v[c] = 0.f;
        }
        union { unsigned u[8]; uint4 q[2]; } o;
        #pragma unroll
        for (int c = 0; c < 8; ++c) o.u[c] = cvt_pk_bf16(v[2 * c], v[2 * c + 1]);
        *(uint4*)&bdst[0] = o.q[0];
        *(uint4*)&bdst[8] = o.q[1];
    } else {
        build_rbf(bdst, xir[gb][0], xjr[row_b][slot - 1], cA, cB);
    }

    // B-read offsets (de-swizzle)
    int boff[2][4];
    #pragma unroll
    for (int ks = 0; ks < 2; ++ks)
        #pragma unroll
        for (int nf = 0; nf < 4; ++nf) {
            int n = nh * 64 + nf * 16 + l16;
            boff[ks][nf] = n * 64 + ((((ks << 2) | lk) ^ (n & 7)) << 3);
        }

    int p = slot + 3, a1 = 0, a2 = slot + 3;   // build target: chunk ch+1
    f32x4 acc[2][4] = {};

    __syncthreads();   // drains async (Bs ch0) + ds_writes (As ch0)

    for (int ch = 0; ch < NCHUNK; ++ch) {
        // (i) frag reads -> regs (drained by barrier-1's waitcnt)
        bf16x8 afr[2][2], bfr[2][4];
        #pragma unroll
        for (int ks = 0; ks < 2; ++ks) {
            afr[ks][0] = *(const bf16x8*)&As[arow0 + ks * 32 + lk8];
            afr[ks][1] = *(const bf16x8*)&As[arow1 + ks * 32 + lk8];
            #pragma unroll
            for (int nf = 0; nf < 4; ++nf)
                bfr[ks][nf] = *(const bf16x8*)&Bs[boff[ks][nf]];
        }
        __syncthreads();   // (ii) all reads complete -> buffers free

        // (iii) prefetch Bs ch+1 + build As ch+1 (overlaps MFMA below)
        if (ch + 1 < NCHUNK) {
            #pragma unroll
            for (int it = 0; it < 4; ++it)
                ASYNC16(Bs + wave * 2048 + it * 512,
                        gsrc + (size_t)it * 8 * KPAD + (ch + 1) * 64);
            if (p <= 195) {
                build_rbf(bdst, xir[gb][a1], xjr[row_b][a2], cA, cB);
            } else {
                uint4 z = {0u, 0u, 0u, 0u};
                *(uint4*)&bdst[0] = z;
                *(uint4*)&bdst[8] = z;
            }
            p += 4; a2 += 4; if (a2 >= 14) { a2 -= 14; ++a1; }
        }

        // (iv) MFMA on registers (priority-boosted; blocks are phase-diverse)
        __builtin_amdgcn_s_setprio(1);
        #pragma unroll
        for (int ks = 0; ks < 2; ++ks)
            #pragma unroll
            for (int mf = 0; mf < 2; ++mf)
                #pragma unroll
                for (int nf = 0; nf < 4; ++nf)
                    acc[mf][nf] = __builtin_amdgcn_mfma_f32_16x16x32_bf16(
                        afr[ks][mf], bfr[ks][nf], acc[mf][nf], 0, 0, 0);
        __builtin_amdgcn_s_setprio(0);

        __syncthreads();   // (v) drains async + build writes -> next chunk ready
    }

    // ---- LayerNorm epilogue (C/D: col = lane&15, row = (lane>>4)*4+reg) ----
    #pragma unroll
    for (int mf = 0; mf < 2; ++mf)
        #pragma unroll
        for (int reg = 0; reg < 4; ++reg) {
            float s = acc[mf][0][reg] + acc[mf][1][reg] + acc[mf][2][reg] + acc[mf][3][reg];
            float q = acc[mf][0][reg] * acc[mf][0][reg] + acc[mf][1][reg] * acc[mf][1][reg]
                    + acc[mf][2][reg] * acc[mf][2][reg] + acc[mf][3][reg] * acc[mf][3][reg];
            #pragma unroll
            for (int m = 1; m < 16; m <<= 1) {
                s += __shfl_xor(s, m);
                q += __shfl_xor(q, m);
            }
            if (l16 == 0) {
                int row = mh * 32 + mf * 16 + lk * 4 + reg;
                lnS[row][nh] = s;
                lnQ[row][nh] = q;
            }
        }
    __syncthreads();

    float gl[4], bl[4];
    #pragma unroll
    for (int nf = 0; nf < 4; ++nf) {
        int col = nh * 64 + nf * 16 + l16;
        gl[nf] = gamma[col];
        bl[nf] = beta[col];
    }
    #pragma unroll
    for (int mf = 0; mf < 2; ++mf)
        #pragma unroll
        for (int reg = 0; reg < 4; ++reg) {
            int r = mh * 32 + mf * 16 + lk * 4 + reg;
            int e = r & 31, g = r >> 5;
            if (e < TOPK) {
                float s = lnS[r][0] + lnS[r][1];
                float q = lnQ[r][0] + lnQ[r][1];
                float mean = s * (1.f / 128.f);
                float var = q * (1.f / 128.f) - mean * mean;
                float inv = 1.f / sqrtf(var + 1e-5f);
                float* dst = &E[((size_t)((i0 + g) * TOPK + e)) * 128];
                #pragma unroll
                for (int nf = 0; nf < 4; ++nf) {
                    int col = nh * 64 + nf * 16 + l16;
                    dst[col] = (acc[mf][nf][reg] - mean) * inv * gl[nf] + bl[nf];
                }
            }
        }
}

// ---------------------------------------------------------------------------
extern "C" void kernel_launch(void* const* d_in, const int* in_sizes, int n_in,
                              void* d_out, int out_size, void* d_ws, size_t ws_size,
                              hipStream_t stream)
{
    const float* x       = (const float*)d_in[0];
    const float* mask    = (const float*)d_in[1];
    const float* a14m    = (const float*)d_in[2];
    const float* feat    = (const float*)d_in[3];
    const float* W_pos   = (const float*)d_in[4];
    const float* b_pos   = (const float*)d_in[5];
    const float* W_edge  = (const float*)d_in[6];
    const float* gamma_e = (const float*)d_in[7];
    const float* beta_e  = (const float*)d_in[8];
    const float* W_node  = (const float*)d_in[9];
    const float* gamma_n = (const float*)d_in[10];
    const float* beta_n  = (const float*)d_in[11];
    const int*   S       = (const int*)d_in[12];
    const int*   R_idx   = (const int*)d_in[13];
    const int*   chain   = (const int*)d_in[14];

    float* out     = (float*)d_out;
    float* V       = out;                                  // 1536*128
    float* E       = out + 196608;                         // 1536*30*128
    float* out_idx = out + 196608 + 5898240;               // 1536*30
    float* out_x   = out_idx + 46080;                      // 1536*14*3

    ushort* Wt = (ushort*)d_ws;                            // 128*3200 bf16

    prep_kernel<<<PREP_BLKS, 512, 0, stream>>>(
        x, mask, feat, W_edge, Wt, W_node, gamma_n, beta_n, S, V, out_idx, out_x);
    edge_mfma_kernel<<<EDGE_BLKS, 256, 0, stream>>>(
        x, mask, a14m, W_pos, b_pos, Wt, gamma_e, beta_e, R_idx, chain,
        out_idx, E);
}